// Round 1
// baseline (413.330 us; speedup 1.0000x reference)
//
#include <hip/hip_runtime.h>
#include <cstdint>

typedef __attribute__((ext_vector_type(4))) float f32x4;
typedef __attribute__((ext_vector_type(16))) float f32x16;
typedef __attribute__((ext_vector_type(8))) __bf16 bf16x8;
typedef __attribute__((ext_vector_type(4))) unsigned short u16x4;
typedef __attribute__((ext_vector_type(2))) unsigned int u32x2;
typedef __attribute__((ext_vector_type(4))) float fvec4;

#define DEV __device__ __forceinline__
#define MFMA16(a, b, c) __builtin_amdgcn_mfma_f32_16x16x32_bf16((a), (b), (c), 0, 0, 0)
#define MFMA32(a, b, c) __builtin_amdgcn_mfma_f32_32x32x16_bf16((a), (b), (c), 0, 0, 0)

// RNE float -> bf16
DEV unsigned short f2bf(float f) {
  union { float f; uint32_t u; } c; c.f = f;
  uint32_t u = c.u;
  return (unsigned short)((u + 0x7FFFu + ((u >> 16) & 1u)) >> 16);
}

// pack two floats to 2 bf16 in one dword (round-half-up, 3 VALU ops)
DEV unsigned int pack2(float lo, float hi) {
  union { float f; uint32_t u; } a, b;
  a.f = lo; b.f = hi;
  return __builtin_amdgcn_perm(b.u + 0x8000u, a.u + 0x8000u, 0x07060302u);
}

// async global->LDS, 16B/lane; LDS dest = wave-uniform base + lane*16
DEV void gll16(const void* g, void* l) {
  __builtin_amdgcn_global_load_lds(
      (const __attribute__((address_space(1))) void*)(uintptr_t)g,
      (__attribute__((address_space(3))) void*)(uint32_t)(uintptr_t)l,
      16, 0, 0);
}

// ---------------- elementwise fp32 -> bf16 ----------------
__global__ void cvt_bf16(const float* __restrict__ src, unsigned short* __restrict__ dst) {
  int i = (blockIdx.x * 256 + threadIdx.x) * 4;
  fvec4 v = *(const fvec4*)(src + i);
  u16x4 o;
  o[0] = f2bf(v[0]); o[1] = f2bf(v[1]); o[2] = f2bf(v[2]); o[3] = f2bf(v[3]);
  *(u16x4*)(dst + i) = o;
}

// ---------------- 4x fused: W [K][N] fp32 -> WT [N][K] bf16 ----------------
__global__ void transpose_cvt4(const float* __restrict__ W0, const float* __restrict__ W1,
                               const float* __restrict__ W2, const float* __restrict__ W3,
                               unsigned short* __restrict__ Dqkv, unsigned short* __restrict__ Do) {
  __shared__ float t[32][33];
  const float* W = blockIdx.z == 0 ? W0 : blockIdx.z == 1 ? W1 : blockIdx.z == 2 ? W2 : W3;
  unsigned short* WT = blockIdx.z < 3 ? Dqkv + (size_t)blockIdx.z * 2048 * 2048 : Do;
  int n0 = blockIdx.x * 32, k0 = blockIdx.y * 32;
  int x = threadIdx.x, y = threadIdx.y;  // block (32,8)
  #pragma unroll
  for (int i = 0; i < 32; i += 8)
    t[y + i][x] = W[(size_t)(k0 + y + i) * 2048 + n0 + x];
  __syncthreads();
  #pragma unroll
  for (int i = 0; i < 32; i += 8)
    WT[(size_t)(n0 + y + i) * 2048 + k0 + x] = f2bf(t[x][y + i]);
}

// softmax scale folded into Q (exp2 domain): rsqrt(DH)*log2(e)
constexpr float QSC = 0.08838834764831845f * 1.4426950408889634f;

// ---------------- 128x128-tile GEMM (MODE 0 only now: C = A@Bt^T + b0, fp32 out) ----------------
template <int MODE>
__global__ __launch_bounds__(256, 2) void gemm128(
    const unsigned short* __restrict__ A,
    const unsigned short* __restrict__ Bt,
    const float* __restrict__ b0, const float* __restrict__ b1,
    const float* __restrict__ b2,
    void* __restrict__ o0, void* __restrict__ o1, void* __restrict__ o2) {
  __shared__ unsigned short As[128 * 64];
  __shared__ unsigned short Bs[128 * 64];
  const int id = blockIdx.x;
  const int m0 = (((id & 7) << 2) | ((id >> 3) & 3)) * 128;
  const int n0 = (id >> 5) * 128;
  const int tid = threadIdx.x;
  const int wave = tid >> 6, lid = tid & 63;
  const int l16 = lid & 15, lq = lid >> 4;
  const int wm = (wave >> 1) * 64, wn = (wave & 1) * 64;

  const int srow = lid >> 3;
  const int sgrp = (lid & 7) ^ srow;

  f32x4 acc[4][4] = {};

  for (int k0 = 0; k0 < 2048; k0 += 64) {
    #pragma unroll
    for (int i = 0; i < 4; ++i) {
      const int t = wave * 4 + i;
      const int r = t * 8 + srow;
      gll16(A + (size_t)(m0 + r) * 2048 + k0 + sgrp * 8, (char*)As + t * 1024 + lid * 16);
      gll16(Bt + (size_t)(n0 + r) * 2048 + k0 + sgrp * 8, (char*)Bs + t * 1024 + lid * 16);
    }
    __syncthreads();
    #pragma unroll
    for (int kk = 0; kk < 2; ++kk) {
      const int G = kk * 4 + lq;
      bf16x8 af[4], bfr[4];
      #pragma unroll
      for (int i = 0; i < 4; ++i)
        af[i] = *(const bf16x8*)(As + (wm + i * 16 + l16) * 64 + ((G ^ (l16 & 7)) << 3));
      #pragma unroll
      for (int j = 0; j < 4; ++j)
        bfr[j] = *(const bf16x8*)(Bs + (wn + j * 16 + l16) * 64 + ((G ^ (l16 & 7)) << 3));
      #pragma unroll
      for (int i = 0; i < 4; ++i)
        #pragma unroll
        for (int j = 0; j < 4; ++j)
          acc[i][j] = MFMA16(af[i], bfr[j], acc[i][j]);
    }
    __syncthreads();
  }

  #pragma unroll
  for (int j = 0; j < 4; ++j) {
    const int c = n0 + wn + j * 16 + l16;
    const float bv = b0[c];
    #pragma unroll
    for (int i = 0; i < 4; ++i)
      #pragma unroll
      for (int r = 0; r < 4; ++r) {
        const int row = m0 + wm + i * 16 + lq * 4 + r;
        ((float*)o0)[(size_t)row * 2048 + c] = acc[i][j][r] + bv;
      }
  }
}

// ---------------- 256x256-tile 8-phase QKV GEMM (T2+T3+T4+T5) ----------------
// 512 thr (8 waves, WARPS 2Mx4N, per-wave 128x64), BK=64, 2 K-tiles/iter.
// LDS 128KB: A[2][256x64], B[2][256x64]. Even K-tiles -> buf0, odd -> buf1.
// B stored row-permuted (L = {n5,n7,n6,n4..n0}) so qn-halves are 64-row aligned
// for linear global_load_lds staging. Chunk-XOR swizzle (c ^ row&7) as in gemm128.
// Phase p: ds_read quadrant (qm,qn) | stage | bar | lgkmcnt(0) | 16 MFMA | bar.
// Stage roles: p0:A1,B1(T+1)  p2:A0(T+2)  p3:B0(T+2)+vmcnt(4)
//              p4:A1,B1(T+2)  p6:A0(T+3)  p7:B0(T+3)+vmcnt(4)
// vmcnt(4) leaves 2 half-tiles in flight; covers each staged half 3-5 phases.
#define STA(c, kt, q) do { \
  _Pragma("unroll") for (int jj = 0; jj < 2; ++jj) { \
    const int j = (q) + jj * 2; \
    const int r = j * 64 + srow; \
    const int g = schk ^ (r & 7); \
    gll16(A + (size_t)(m0 + r) * 2048 + ((kt) << 6) + g * 8, \
          (char*)Als + (c) * 32768 + j * 8192 + tid * 16); \
  } } while (0)

#define STB(c, kt, q) do { \
  _Pragma("unroll") for (int jj = 0; jj < 2; ++jj) { \
    const int j = (q) * 2 + jj; \
    const int L = j * 64 + srow; \
    const int n = (((L & 127) >> 5) << 6) + ((L >> 7) << 5) + (L & 31); \
    const int g = schk ^ (L & 7); \
    gll16(Bt + (size_t)(n0 + n) * 2048 + ((kt) << 6) + g * 8, \
          (char*)Bls + (c) * 32768 + j * 8192 + tid * 16); \
  } } while (0)

#define PHASE(CUR, QM, QN, STAGE, VM) do { \
  bf16x8 af[4][2], bf_[2][2]; \
  const unsigned short* Ab = Als + (CUR) * 16384; \
  const unsigned short* Bb = Bls + (CUR) * 16384; \
  _Pragma("unroll") for (int m = 0; m < 4; ++m) { \
    const int row = wr * 128 + ((QM) * 4 + m) * 16 + l16; \
    _Pragma("unroll") for (int kk = 0; kk < 2; ++kk) \
      af[m][kk] = *(const bf16x8*)(Ab + row * 64 + (((kk * 4 + lq) ^ (row & 7)) << 3)); \
  } \
  _Pragma("unroll") for (int n = 0; n < 2; ++n) { \
    const int bg = wc * 64 + ((QN) * 2 + n) * 16 + l16; \
    const int L = (((bg >> 5) & 1) << 7) | ((bg >> 6) << 5) | (bg & 31); \
    _Pragma("unroll") for (int kk = 0; kk < 2; ++kk) \
      bf_[n][kk] = *(const bf16x8*)(Bb + L * 64 + (((kk * 4 + lq) ^ (L & 7)) << 3)); \
  } \
  STAGE; \
  __builtin_amdgcn_sched_barrier(0); \
  __builtin_amdgcn_s_barrier(); \
  asm volatile("s_waitcnt lgkmcnt(0)" ::: "memory"); \
  __builtin_amdgcn_sched_barrier(0); \
  __builtin_amdgcn_s_setprio(1); \
  _Pragma("unroll") for (int m = 0; m < 4; ++m) \
    _Pragma("unroll") for (int n = 0; n < 2; ++n) \
      _Pragma("unroll") for (int kk = 0; kk < 2; ++kk) \
        acc[(QM) * 4 + m][(QN) * 2 + n] = \
            MFMA16(af[m][kk], bf_[n][kk], acc[(QM) * 4 + m][(QN) * 2 + n]); \
  __builtin_amdgcn_s_setprio(0); \
  __builtin_amdgcn_sched_barrier(0); \
  VM; \
  __builtin_amdgcn_s_barrier(); \
} while (0)

__global__ __launch_bounds__(512, 2) void gemm256qkv(
    const unsigned short* __restrict__ A,
    const unsigned short* __restrict__ Bt,
    const float* __restrict__ b0, const float* __restrict__ b1,
    const float* __restrict__ b2,
    unsigned short* __restrict__ oQ, unsigned short* __restrict__ oK,
    unsigned short* __restrict__ oV) {
  __shared__ unsigned short Als[32768];  // [2 bufs][256 rows][64 k]
  __shared__ unsigned short Bls[32768];

  const int id = blockIdx.x;                    // 384 blocks, 384%8==0
  const int wg = (id & 7) * 48 + (id >> 3);     // XCD swizzle: 48 blocks/XCD
  const int mt = wg / 24, nt = wg % 24;         // 2 A-panels/XCD stay L2-hot
  const int m0 = mt << 8, n0 = nt << 8;

  const int tid = threadIdx.x;
  const int wave = tid >> 6, lid = tid & 63;
  const int l16 = lid & 15, lq = lid >> 4;
  const int wr = wave >> 2, wc = wave & 3;
  const int srow = tid >> 3;  // staging: row-in-issue
  const int schk = tid & 7;   // staging: 16B chunk

  f32x4 acc[8][4] = {};

  // prologue: tile0 full + tile1 A0,B0; wait tile0 (4 newest stay in flight)
  STA(0, 0, 0); STA(0, 0, 1); STB(0, 0, 0); STB(0, 0, 1);
  STA(1, 1, 0); STB(1, 1, 0);
  asm volatile("s_waitcnt vmcnt(4)" ::: "memory");
  __builtin_amdgcn_s_barrier();

  #pragma unroll 1
  for (int i = 0; i < 16; ++i) {
    const int t1 = 2 * i + 1;
    const int t2 = (2 * i + 2 < 32) ? 2 * i + 2 : 31;  // clamp: tail stages are dead
    const int t3 = (2 * i + 3 < 32) ? 2 * i + 3 : 31;
    PHASE(0, 0, 0, { STA(1, t1, 1); STB(1, t1, 1); }, );
    PHASE(0, 0, 1, , );
    PHASE(0, 1, 0, STA(0, t2, 0), );
    PHASE(0, 1, 1, STB(0, t2, 0), asm volatile("s_waitcnt vmcnt(4)" ::: "memory"));
    PHASE(1, 0, 0, { STA(0, t2, 1); STB(0, t2, 1); }, );
    PHASE(1, 0, 1, , );
    PHASE(1, 1, 0, STA(1, t3, 0), );
    PHASE(1, 1, 1, STB(1, t3, 0), asm volatile("s_waitcnt vmcnt(4)" ::: "memory"));
  }

  // epilogue: QKV split + bias; Q scaled; V transposed to [bh][d][s]
  const int which = n0 >> 11;  // 0=Q 1=K 2=V (n0 multiple of 256, no straddle)
  const float* bp = which == 0 ? b0 : which == 1 ? b1 : b2;
  #pragma unroll
  for (int n = 0; n < 4; ++n) {
    const int hd = (n0 & 2047) + wc * 64 + n * 16 + l16;
    const int h = hd >> 7, d = hd & 127;
    const float bv = bp[hd];
    if (which == 2) {
      #pragma unroll
      for (int m = 0; m < 8; ++m) {
        const int row0 = m0 + wr * 128 + m * 16 + lq * 4;
        const int bb = row0 >> 11, s0 = row0 & 2047;
        u16x4 pv;
        #pragma unroll
        for (int r = 0; r < 4; ++r) pv[r] = f2bf(acc[m][n][r] + bv);
        *(u16x4*)(oV + ((size_t)((bb * 16 + h) * 128 + d)) * 2048 + s0) = pv;
      }
    } else {
      const float sc = which == 0 ? QSC : 1.0f;
      unsigned short* op = which == 0 ? oQ : oK;
      #pragma unroll
      for (int m = 0; m < 8; ++m)
        #pragma unroll
        for (int r = 0; r < 4; ++r) {
          const int row = m0 + wr * 128 + m * 16 + lq * 4 + r;
          const int bb = row >> 11, s = row & 2047;
          op[(size_t)((bb * 16 + h) * 2048 + s) * 128 + d] = f2bf((acc[m][n][r] + bv) * sc);
        }
    }
  }
}

// ---------------- flash attention: 32x32x16 MFMA, 128-q blocks ----------------
__global__ __launch_bounds__(256, 2) void attn(
    const unsigned short* __restrict__ Q,
    const unsigned short* __restrict__ K,
    const unsigned short* __restrict__ Vt,
    unsigned short* __restrict__ ctx) {
  __shared__ unsigned short Ks[64 * 128];      // [kr][16B-chunk ^ (kr&15)] 16KB
  __shared__ unsigned short Vts[128 * 64];     // [d][16B-chunk ^ (d&7)]    16KB
  __shared__ unsigned short Ps[4 * 32 * 64];   // per-wave [q][chunk ^ (q&7)] 16KB

  const int bh = blockIdx.y;
  const int jq = (bh < 16) ? (15 - (int)blockIdx.x) : (int)blockIdx.x;
  const int q0 = jq * 128;
  const int b = bh >> 4, h = bh & 15;
  const unsigned short* Qh = Q + (size_t)bh * 2048 * 128;
  const unsigned short* Kh = K + (size_t)bh * 2048 * 128;
  const unsigned short* Vth = Vt + (size_t)bh * 128 * 2048;

  const int tid = threadIdx.x;
  const int wave = tid >> 6, lid = tid & 63;
  const int l32 = lid & 31, half = lid >> 5;
  const int qrow = q0 + wave * 32 + l32;
  unsigned short* Pw = Ps + wave * 2048 + l32 * 64;
  const int qsw = l32 & 7;

  bf16x8 qf[8];
  #pragma unroll
  for (int ds = 0; ds < 8; ++ds)
    qf[ds] = *(const bf16x8*)(Qh + (size_t)qrow * 128 + ds * 16 + half * 8);

  float m_i = -1e30f, l_i = 0.f;
  f32x16 acc[4] = {};

  const int ntiles = 2 * jq + 2;
  for (int jt = 0; jt < ntiles; ++jt) {
    const int k0 = jt * 64;
    #pragma unroll
    for (int ii = 0; ii < 4; ++ii) {
      const int t = wave * 4 + ii;
      const int r = t * 4 + (lid >> 4);
      const int g = (lid & 15) ^ (r & 15);
      gll16(Kh + (size_t)(k0 + r) * 128 + g * 8, (char*)Ks + t * 1024 + lid * 16);
    }
    #pragma unroll
    for (int ii = 0; ii < 4; ++ii) {
      const int t = wave * 4 + ii;
      const int d = t * 8 + (lid >> 3);
      const int g = (lid & 7) ^ (d & 7);
      gll16(Vth + (size_t)d * 2048 + k0 + g * 8, (char*)Vts + t * 1024 + lid * 16);
    }
    __syncthreads();

    f32x16 sacc[2] = {};
    #pragma unroll
    for (int ds = 0; ds < 8; ++ds) {
      #pragma unroll
      for (int mb = 0; mb < 2; ++mb) {
        const int kr = mb * 32 + l32;
        bf16x8 af = *(const bf16x8*)(Ks + kr * 128 + (((ds * 2 + half) ^ (kr & 15)) << 3));
        sacc[mb] = MFMA32(af, qf[ds], sacc[mb]);
      }
    }

    if (jt >= 2 * jq) {
      #pragma unroll
      for (int mb = 0; mb < 2; ++mb)
        #pragma unroll
        for (int i = 0; i < 16; ++i) {
          const int kg = k0 + mb * 32 + (i & 3) + 8 * (i >> 2) + 4 * half;
          if (kg > qrow) sacc[mb][i] = -1e30f;
        }
    }

    float tmax = -1e30f;
    #pragma unroll
    for (int mb = 0; mb < 2; ++mb)
      #pragma unroll
      for (int i = 0; i < 16; ++i) tmax = fmaxf(tmax, sacc[mb][i]);
    tmax = fmaxf(tmax, __shfl_xor(tmax, 32));

    const float mnew = fmaxf(m_i, tmax);
    const float alpha = exp2f(m_i - mnew);
    m_i = mnew;

    float ps = 0.f;
    #pragma unroll
    for (int mb = 0; mb < 2; ++mb) {
      #pragma unroll
      for (int i = 0; i < 16; ++i) {
        sacc[mb][i] = exp2f(sacc[mb][i] - mnew);
        ps += sacc[mb][i];
      }
      #pragma unroll
      for (int u = 0; u < 4; ++u) {
        u32x2 w;
        w[0] = pack2(sacc[mb][4 * u], sacc[mb][4 * u + 1]);
        w[1] = pack2(sacc[mb][4 * u + 2], sacc[mb][4 * u + 3]);
        *(u32x2*)(Pw + (((u + mb * 4) ^ qsw) << 3) + half * 4) = w;
      }
    }
    ps += __shfl_xor(ps, 32);
    l_i = l_i * alpha + ps;
    #pragma unroll
    for (int db = 0; db < 4; ++db)
      #pragma unroll
      for (int i = 0; i < 16; ++i) acc[db][i] *= alpha;

    #pragma unroll
    for (int ks = 0; ks < 4; ++ks) {
      bf16x8 pf = *(const bf16x8*)(Pw + (((ks * 2 + half) ^ qsw) << 3));
      #pragma unroll
      for (int db = 0; db < 4; ++db) {
        const int d = db * 32 + l32;
        bf16x8 vf = *(const bf16x8*)(Vts + d * 64 + (((ks * 2 + half) ^ (d & 7)) << 3));
        acc[db] = MFMA32(vf, pf, acc[db]);
      }
    }
    __syncthreads();
  }

  const float inv = 1.f / l_i;
  const size_t base = ((size_t)(b * 2048 + qrow)) * 2048 + h * 128;
  #pragma unroll
  for (int db = 0; db < 4; ++db) {
    #pragma unroll
    for (int u = 0; u < 4; ++u) {
      u32x2 w;
      w[0] = pack2(acc[db][4 * u] * inv, acc[db][4 * u + 1] * inv);
      w[1] = pack2(acc[db][4 * u + 2] * inv, acc[db][4 * u + 3] * inv);
      *(u32x2*)(ctx + base + db * 32 + 8 * u + 4 * half) = w;
    }
  }
}

// ---------------- launch ----------------
extern "C" void kernel_launch(void* const* d_in, const int* in_sizes, int n_in,
                              void* d_out, int out_size, void* d_ws, size_t ws_size,
                              hipStream_t stream) {
  const float* hs = (const float*)d_in[0];
  const float* Wq = (const float*)d_in[1];
  const float* bq = (const float*)d_in[2];
  const float* Wk = (const float*)d_in[3];
  const float* bk = (const float*)d_in[4];
  const float* Wv = (const float*)d_in[5];
  const float* bv = (const float*)d_in[6];
  const float* Wo = (const float*)d_in[7];
  const float* bo = (const float*)d_in[8];
  float* out = (float*)d_out;

  char* ws = (char*)d_ws;
  unsigned short* hsb   = (unsigned short*)(ws);              // 16 MB [4096][2048]
  unsigned short* wqkvt = (unsigned short*)(ws + (16 << 20)); // 24 MB [6144][2048]
  unsigned short* wot   = (unsigned short*)(ws + (40 << 20)); //  8 MB
  unsigned short* Qb    = (unsigned short*)(ws + (48 << 20)); // 16 MB [bh][s][d]
  unsigned short* Kb    = (unsigned short*)(ws + (64 << 20)); // 16 MB [bh][s][d]
  unsigned short* Vtb   = (unsigned short*)(ws + (80 << 20)); // 16 MB [bh][d][s]
  unsigned short* ctx   = (unsigned short*)(ws + (96 << 20)); // 16 MB [4096][2048]

  cvt_bf16<<<dim3(8192), dim3(256), 0, stream>>>(hs, hsb);
  transpose_cvt4<<<dim3(64, 64, 4), dim3(32, 8), 0, stream>>>(Wq, Wk, Wv, Wo, wqkvt, wot);

  gemm256qkv<<<dim3(384), dim3(512), 0, stream>>>(hsb, wqkvt, bq, bk, bv, Qb, Kb, Vtb);
  attn<<<dim3(16, 32), 256, 0, stream>>>(Qb, Kb, Vtb, ctx);
  gemm128<0><<<dim3(512), 256, 0, stream>>>(ctx, wot, bo, nullptr, nullptr,
                                            (void*)out, nullptr, nullptr);
}

// Round 2
// 389.009 us; speedup vs baseline: 1.0625x; 1.0625x over previous
//
#include <hip/hip_runtime.h>
#include <cstdint>

typedef __attribute__((ext_vector_type(4))) float f32x4;
typedef __attribute__((ext_vector_type(16))) float f32x16;
typedef __attribute__((ext_vector_type(8))) __bf16 bf16x8;
typedef __attribute__((ext_vector_type(4))) unsigned short u16x4;
typedef __attribute__((ext_vector_type(2))) unsigned int u32x2;
typedef __attribute__((ext_vector_type(4))) float fvec4;

#define DEV __device__ __forceinline__
#define MFMA16(a, b, c) __builtin_amdgcn_mfma_f32_16x16x32_bf16((a), (b), (c), 0, 0, 0)
#define MFMA32(a, b, c) __builtin_amdgcn_mfma_f32_32x32x16_bf16((a), (b), (c), 0, 0, 0)

// RNE float -> bf16
DEV unsigned short f2bf(float f) {
  union { float f; uint32_t u; } c; c.f = f;
  uint32_t u = c.u;
  return (unsigned short)((u + 0x7FFFu + ((u >> 16) & 1u)) >> 16);
}

// pack two floats to 2 bf16 in one dword (round-half-up, 3 VALU ops)
DEV unsigned int pack2(float lo, float hi) {
  union { float f; uint32_t u; } a, b;
  a.f = lo; b.f = hi;
  return __builtin_amdgcn_perm(b.u + 0x8000u, a.u + 0x8000u, 0x07060302u);
}

// async global->LDS, 16B/lane; LDS dest = wave-uniform base + lane*16
DEV void gll16(const void* g, void* l) {
  __builtin_amdgcn_global_load_lds(
      (const __attribute__((address_space(1))) void*)(uintptr_t)g,
      (__attribute__((address_space(3))) void*)(uint32_t)(uintptr_t)l,
      16, 0, 0);
}

// ---------------- elementwise fp32 -> bf16 ----------------
__global__ void cvt_bf16(const float* __restrict__ src, unsigned short* __restrict__ dst) {
  int i = (blockIdx.x * 256 + threadIdx.x) * 4;
  fvec4 v = *(const fvec4*)(src + i);
  u16x4 o;
  o[0] = f2bf(v[0]); o[1] = f2bf(v[1]); o[2] = f2bf(v[2]); o[3] = f2bf(v[3]);
  *(u16x4*)(dst + i) = o;
}

// ---------------- 4x fused: W [K][N] fp32 -> WT [N][K] bf16 ----------------
__global__ void transpose_cvt4(const float* __restrict__ W0, const float* __restrict__ W1,
                               const float* __restrict__ W2, const float* __restrict__ W3,
                               unsigned short* __restrict__ Dqkv, unsigned short* __restrict__ Do) {
  __shared__ float t[32][33];
  const float* W = blockIdx.z == 0 ? W0 : blockIdx.z == 1 ? W1 : blockIdx.z == 2 ? W2 : W3;
  unsigned short* WT = blockIdx.z < 3 ? Dqkv + (size_t)blockIdx.z * 2048 * 2048 : Do;
  int n0 = blockIdx.x * 32, k0 = blockIdx.y * 32;
  int x = threadIdx.x, y = threadIdx.y;  // block (32,8)
  #pragma unroll
  for (int i = 0; i < 32; i += 8)
    t[y + i][x] = W[(size_t)(k0 + y + i) * 2048 + n0 + x];
  __syncthreads();
  #pragma unroll
  for (int i = 0; i < 32; i += 8)
    WT[(size_t)(n0 + y + i) * 2048 + k0 + x] = f2bf(t[x][y + i]);
}

// softmax scale folded into Q (exp2 domain): rsqrt(DH)*log2(e)
constexpr float QSC = 0.08838834764831845f * 1.4426950408889634f;

// ---------------- 128x128-tile GEMM (MODE 0: C = A@Bt^T + b0, fp32 out) ----------------
template <int MODE>
__global__ __launch_bounds__(256, 2) void gemm128(
    const unsigned short* __restrict__ A,
    const unsigned short* __restrict__ Bt,
    const float* __restrict__ b0, const float* __restrict__ b1,
    const float* __restrict__ b2,
    void* __restrict__ o0, void* __restrict__ o1, void* __restrict__ o2) {
  __shared__ unsigned short As[128 * 64];
  __shared__ unsigned short Bs[128 * 64];
  const int id = blockIdx.x;
  const int m0 = (((id & 7) << 2) | ((id >> 3) & 3)) * 128;
  const int n0 = (id >> 5) * 128;
  const int tid = threadIdx.x;
  const int wave = tid >> 6, lid = tid & 63;
  const int l16 = lid & 15, lq = lid >> 4;
  const int wm = (wave >> 1) * 64, wn = (wave & 1) * 64;

  const int srow = lid >> 3;
  const int sgrp = (lid & 7) ^ srow;

  f32x4 acc[4][4] = {};

  for (int k0 = 0; k0 < 2048; k0 += 64) {
    #pragma unroll
    for (int i = 0; i < 4; ++i) {
      const int t = wave * 4 + i;
      const int r = t * 8 + srow;
      gll16(A + (size_t)(m0 + r) * 2048 + k0 + sgrp * 8, (char*)As + t * 1024 + lid * 16);
      gll16(Bt + (size_t)(n0 + r) * 2048 + k0 + sgrp * 8, (char*)Bs + t * 1024 + lid * 16);
    }
    __syncthreads();
    #pragma unroll
    for (int kk = 0; kk < 2; ++kk) {
      const int G = kk * 4 + lq;
      bf16x8 af[4], bfr[4];
      #pragma unroll
      for (int i = 0; i < 4; ++i)
        af[i] = *(const bf16x8*)(As + (wm + i * 16 + l16) * 64 + ((G ^ (l16 & 7)) << 3));
      #pragma unroll
      for (int j = 0; j < 4; ++j)
        bfr[j] = *(const bf16x8*)(Bs + (wn + j * 16 + l16) * 64 + ((G ^ (l16 & 7)) << 3));
      #pragma unroll
      for (int i = 0; i < 4; ++i)
        #pragma unroll
        for (int j = 0; j < 4; ++j)
          acc[i][j] = MFMA16(af[i], bfr[j], acc[i][j]);
    }
    __syncthreads();
  }

  #pragma unroll
  for (int j = 0; j < 4; ++j) {
    const int c = n0 + wn + j * 16 + l16;
    const float bv = b0[c];
    #pragma unroll
    for (int i = 0; i < 4; ++i)
      #pragma unroll
      for (int r = 0; r < 4; ++r) {
        const int row = m0 + wm + i * 16 + lq * 4 + r;
        ((float*)o0)[(size_t)row * 2048 + c] = acc[i][j][r] + bv;
      }
  }
}

// ---------------- 128x256-tile 4-phase QKV GEMM ----------------
// Grid 768 = 3 exact rounds of 256 CUs (perfect packing; the 256^2 version's
// 384 blocks paid a 25% idle tax). 8 waves 2Mx4N, per-wave 64x64, BK=64.
// LDS 96KB: A[2][128][64] 32KB + B[2][256][64] 64KB -> 1 block/CU, 2 waves/SIMD.
// Minimum LDS reads: 16 ds_read_b128 / K-tile / lane (was 48 in round-1):
//   P0: read A-half0 (4) + B-full (8), 16 MFMA;  P1: read A-half1 (4), 16 MFMA
// (B fragments held in registers across the pair; 48 frag VGPRs + 64 acc).
// Stage roles (counted vmcnt, never 0 in loop):
//   P0: A(t1) [2 gll]   P1: B(t2) [4] + vmcnt(4)  (completes t1's 6)
//   P2: A(t2) [2]       P3: B(t3) [4] + vmcnt(4)  (completes t2's 6)
// Hazards: every staged region has >=1 full barrier after its last ds_read
// (A units span both halves -> staged only after the half1 read phase; B after
// its full-read phase). Buffer ready exactly one phase before first read.
__global__ __launch_bounds__(512, 2) void gemmqkv(
    const unsigned short* __restrict__ A,
    const unsigned short* __restrict__ Bt,
    const float* __restrict__ b0, const float* __restrict__ b1,
    const float* __restrict__ b2,
    unsigned short* __restrict__ oQ, unsigned short* __restrict__ oK,
    unsigned short* __restrict__ oV) {
  __shared__ unsigned short Als[2 * 128 * 64];  // 32 KB
  __shared__ unsigned short Bls[2 * 256 * 64];  // 64 KB

  const int id = blockIdx.x;            // 768 blocks
  const int xcd = id & 7, loc = id >> 3;  // loc 0..95
  const int mt = loc & 31, ntl = loc >> 5;  // 32 m-tiles, 3 n-cols per XCD
  const int nt = xcd * 3 + ntl;           // each XCD: 3 B-panels L2-hot, A via L3
  const int m0 = mt << 7, n0 = nt << 8;

  const int tid = threadIdx.x;
  const int wave = tid >> 6, lid = tid & 63;
  const int l16 = lid & 15, lq = lid >> 4;
  const int wr = wave >> 2, wc = wave & 3;  // 2M x 4N waves
  const int srow = tid >> 3;   // staging row-in-unit (0..63)
  const int g8 = ((tid & 7) ^ (srow & 7)) * 8;  // pre-swizzled global k-chunk

  f32x4 acc[4][4] = {};
  bf16x8 aq[2][2], bq[4][2];

#define STA_(c, kt) do { \
    _Pragma("unroll") for (int u = 0; u < 2; ++u) \
      gll16(A + (size_t)(m0 + u * 64 + srow) * 2048 + ((kt) << 6) + g8, \
            (char*)Als + (c) * 16384 + u * 8192 + tid * 16); \
  } while (0)

#define STB_(c, kt) do { \
    _Pragma("unroll") for (int u = 0; u < 4; ++u) \
      gll16(Bt + (size_t)(n0 + u * 64 + srow) * 2048 + ((kt) << 6) + g8, \
            (char*)Bls + (c) * 32768 + u * 8192 + tid * 16); \
  } while (0)

#define RDA_(c, h) do { \
    _Pragma("unroll") for (int m = 0; m < 2; ++m) { \
      const int row = wr * 64 + ((h) * 2 + m) * 16 + l16; \
      _Pragma("unroll") for (int kk = 0; kk < 2; ++kk) \
        aq[m][kk] = *(const bf16x8*)(Als + (c) * 8192 + row * 64 + \
                                     (((kk * 4 + lq) ^ (row & 7)) << 3)); \
    } } while (0)

#define RDB_(c) do { \
    _Pragma("unroll") for (int n = 0; n < 4; ++n) { \
      const int bg = wc * 64 + n * 16 + l16; \
      _Pragma("unroll") for (int kk = 0; kk < 2; ++kk) \
        bq[n][kk] = *(const bf16x8*)(Bls + (c) * 16384 + bg * 64 + \
                                     (((kk * 4 + lq) ^ (bg & 7)) << 3)); \
    } } while (0)

#define MM_(h) do { \
    _Pragma("unroll") for (int m = 0; m < 2; ++m) \
      _Pragma("unroll") for (int n = 0; n < 4; ++n) \
        _Pragma("unroll") for (int kk = 0; kk < 2; ++kk) \
          acc[(h) * 2 + m][n] = MFMA16(aq[m][kk], bq[n][kk], acc[(h) * 2 + m][n]); \
  } while (0)

#define SB_ __builtin_amdgcn_sched_barrier(0)
#define BAR_ __builtin_amdgcn_s_barrier()
#define LGKM_ asm volatile("s_waitcnt lgkmcnt(0)" ::: "memory")
#define VM4_ asm volatile("s_waitcnt vmcnt(4)" ::: "memory")

  // prologue: B(t0)[4] A(t0)[2] B(t1)[4] -> vmcnt(4) completes t0's 6
  STB_(0, 0); STA_(0, 0); STB_(1, 1);
  VM4_;
  BAR_;

  #pragma unroll 1
  for (int i = 0; i < 16; ++i) {
    const int t1 = 2 * i + 1;
    const int t2 = (2 * i + 2 < 32) ? 2 * i + 2 : 31;  // clamped tail restage is
    const int t3 = (2 * i + 3 < 32) ? 2 * i + 3 : 31;  // hazard-safe (see notes)
    // P0: buf0 half0 (A-half0 + B-full reads)
    RDA_(0, 0); RDB_(0); STA_(1, t1);
    SB_; BAR_; LGKM_; SB_;
    __builtin_amdgcn_s_setprio(1); MM_(0); __builtin_amdgcn_s_setprio(0);
    SB_; BAR_;
    // P1: buf0 half1
    RDA_(0, 1); STB_(0, t2);
    SB_; BAR_; LGKM_; SB_;
    __builtin_amdgcn_s_setprio(1); MM_(1); __builtin_amdgcn_s_setprio(0);
    SB_; VM4_; BAR_;   // t1 complete -> buf1 ready
    // P2: buf1 half0
    RDA_(1, 0); RDB_(1); STA_(0, t2);
    SB_; BAR_; LGKM_; SB_;
    __builtin_amdgcn_s_setprio(1); MM_(0); __builtin_amdgcn_s_setprio(0);
    SB_; BAR_;
    // P3: buf1 half1
    RDA_(1, 1); STB_(1, t3);
    SB_; BAR_; LGKM_; SB_;
    __builtin_amdgcn_s_setprio(1); MM_(1); __builtin_amdgcn_s_setprio(0);
    SB_; VM4_; BAR_;   // t2 complete -> buf0 ready
  }
  asm volatile("s_waitcnt vmcnt(0)" ::: "memory");  // drain dead tail stages

  // epilogue: QKV split + bias; Q scaled; V transposed to [bh][d][s]
  const int which = n0 >> 11;  // 0=Q 1=K 2=V (n0 multiple of 256, no straddle)
  const float* bp = which == 0 ? b0 : which == 1 ? b1 : b2;
  #pragma unroll
  for (int n = 0; n < 4; ++n) {
    const int hd = (n0 & 2047) + wc * 64 + n * 16 + l16;
    const int h = hd >> 7, d = hd & 127;
    const float bv = bp[hd];
    if (which == 2) {
      #pragma unroll
      for (int m = 0; m < 4; ++m) {
        const int row0 = m0 + wr * 64 + m * 16 + lq * 4;
        const int bb = row0 >> 11, s0 = row0 & 2047;
        u16x4 pv;
        #pragma unroll
        for (int r = 0; r < 4; ++r) pv[r] = f2bf(acc[m][n][r] + bv);
        *(u16x4*)(oV + ((size_t)((bb * 16 + h) * 128 + d)) * 2048 + s0) = pv;
      }
    } else {
      const float sc = which == 0 ? QSC : 1.0f;
      unsigned short* op = which == 0 ? oQ : oK;
      #pragma unroll
      for (int m = 0; m < 4; ++m)
        #pragma unroll
        for (int r = 0; r < 4; ++r) {
          const int row = m0 + wr * 64 + m * 16 + lq * 4 + r;
          const int bb = row >> 11, s = row & 2047;
          op[(size_t)((bb * 16 + h) * 2048 + s) * 128 + d] = f2bf((acc[m][n][r] + bv) * sc);
        }
    }
  }
#undef STA_
#undef STB_
#undef RDA_
#undef RDB_
#undef MM_
#undef SB_
#undef BAR_
#undef LGKM_
#undef VM4_
}

// ---------------- flash attention: 32x32x16 MFMA, 128-q blocks ----------------
__global__ __launch_bounds__(256, 2) void attn(
    const unsigned short* __restrict__ Q,
    const unsigned short* __restrict__ K,
    const unsigned short* __restrict__ Vt,
    unsigned short* __restrict__ ctx) {
  __shared__ unsigned short Ks[64 * 128];      // [kr][16B-chunk ^ (kr&15)] 16KB
  __shared__ unsigned short Vts[128 * 64];     // [d][16B-chunk ^ (d&7)]    16KB
  __shared__ unsigned short Ps[4 * 32 * 64];   // per-wave [q][chunk ^ (q&7)] 16KB

  const int bh = blockIdx.y;
  const int jq = (bh < 16) ? (15 - (int)blockIdx.x) : (int)blockIdx.x;
  const int q0 = jq * 128;
  const int b = bh >> 4, h = bh & 15;
  const unsigned short* Qh = Q + (size_t)bh * 2048 * 128;
  const unsigned short* Kh = K + (size_t)bh * 2048 * 128;
  const unsigned short* Vth = Vt + (size_t)bh * 128 * 2048;

  const int tid = threadIdx.x;
  const int wave = tid >> 6, lid = tid & 63;
  const int l32 = lid & 31, half = lid >> 5;
  const int qrow = q0 + wave * 32 + l32;
  unsigned short* Pw = Ps + wave * 2048 + l32 * 64;
  const int qsw = l32 & 7;

  bf16x8 qf[8];
  #pragma unroll
  for (int ds = 0; ds < 8; ++ds)
    qf[ds] = *(const bf16x8*)(Qh + (size_t)qrow * 128 + ds * 16 + half * 8);

  float m_i = -1e30f, l_i = 0.f;
  f32x16 acc[4] = {};

  const int ntiles = 2 * jq + 2;
  for (int jt = 0; jt < ntiles; ++jt) {
    const int k0 = jt * 64;
    #pragma unroll
    for (int ii = 0; ii < 4; ++ii) {
      const int t = wave * 4 + ii;
      const int r = t * 4 + (lid >> 4);
      const int g = (lid & 15) ^ (r & 15);
      gll16(Kh + (size_t)(k0 + r) * 128 + g * 8, (char*)Ks + t * 1024 + lid * 16);
    }
    #pragma unroll
    for (int ii = 0; ii < 4; ++ii) {
      const int t = wave * 4 + ii;
      const int d = t * 8 + (lid >> 3);
      const int g = (lid & 7) ^ (d & 7);
      gll16(Vth + (size_t)d * 2048 + k0 + g * 8, (char*)Vts + t * 1024 + lid * 16);
    }
    __syncthreads();

    f32x16 sacc[2] = {};
    #pragma unroll
    for (int ds = 0; ds < 8; ++ds) {
      #pragma unroll
      for (int mb = 0; mb < 2; ++mb) {
        const int kr = mb * 32 + l32;
        bf16x8 af = *(const bf16x8*)(Ks + kr * 128 + (((ds * 2 + half) ^ (kr & 15)) << 3));
        sacc[mb] = MFMA32(af, qf[ds], sacc[mb]);
      }
    }

    if (jt >= 2 * jq) {
      #pragma unroll
      for (int mb = 0; mb < 2; ++mb)
        #pragma unroll
        for (int i = 0; i < 16; ++i) {
          const int kg = k0 + mb * 32 + (i & 3) + 8 * (i >> 2) + 4 * half;
          if (kg > qrow) sacc[mb][i] = -1e30f;
        }
    }

    float tmax = -1e30f;
    #pragma unroll
    for (int mb = 0; mb < 2; ++mb)
      #pragma unroll
      for (int i = 0; i < 16; ++i) tmax = fmaxf(tmax, sacc[mb][i]);
    tmax = fmaxf(tmax, __shfl_xor(tmax, 32));

    const float mnew = fmaxf(m_i, tmax);
    const float alpha = exp2f(m_i - mnew);
    m_i = mnew;

    float ps = 0.f;
    #pragma unroll
    for (int mb = 0; mb < 2; ++mb) {
      #pragma unroll
      for (int i = 0; i < 16; ++i) {
        sacc[mb][i] = exp2f(sacc[mb][i] - mnew);
        ps += sacc[mb][i];
      }
      #pragma unroll
      for (int u = 0; u < 4; ++u) {
        u32x2 w;
        w[0] = pack2(sacc[mb][4 * u], sacc[mb][4 * u + 1]);
        w[1] = pack2(sacc[mb][4 * u + 2], sacc[mb][4 * u + 3]);
        *(u32x2*)(Pw + (((u + mb * 4) ^ qsw) << 3) + half * 4) = w;
      }
    }
    ps += __shfl_xor(ps, 32);
    l_i = l_i * alpha + ps;
    #pragma unroll
    for (int db = 0; db < 4; ++db)
      #pragma unroll
      for (int i = 0; i < 16; ++i) acc[db][i] *= alpha;

    #pragma unroll
    for (int ks = 0; ks < 4; ++ks) {
      bf16x8 pf = *(const bf16x8*)(Pw + (((ks * 2 + half) ^ qsw) << 3));
      #pragma unroll
      for (int db = 0; db < 4; ++db) {
        const int d = db * 32 + l32;
        bf16x8 vf = *(const bf16x8*)(Vts + d * 64 + (((ks * 2 + half) ^ (d & 7)) << 3));
        acc[db] = MFMA32(vf, pf, acc[db]);
      }
    }
    __syncthreads();
  }

  const float inv = 1.f / l_i;
  const size_t base = ((size_t)(b * 2048 + qrow)) * 2048 + h * 128;
  #pragma unroll
  for (int db = 0; db < 4; ++db) {
    #pragma unroll
    for (int u = 0; u < 4; ++u) {
      u32x2 w;
      w[0] = pack2(acc[db][4 * u] * inv, acc[db][4 * u + 1] * inv);
      w[1] = pack2(acc[db][4 * u + 2] * inv, acc[db][4 * u + 3] * inv);
      *(u32x2*)(ctx + base + db * 32 + 8 * u + 4 * half) = w;
    }
  }
}

// ---------------- launch ----------------
extern "C" void kernel_launch(void* const* d_in, const int* in_sizes, int n_in,
                              void* d_out, int out_size, void* d_ws, size_t ws_size,
                              hipStream_t stream) {
  const float* hs = (const float*)d_in[0];
  const float* Wq = (const float*)d_in[1];
  const float* bq = (const float*)d_in[2];
  const float* Wk = (const float*)d_in[3];
  const float* bk = (const float*)d_in[4];
  const float* Wv = (const float*)d_in[5];
  const float* bv = (const float*)d_in[6];
  const float* Wo = (const float*)d_in[7];
  const float* bo = (const float*)d_in[8];
  float* out = (float*)d_out;

  char* ws = (char*)d_ws;
  unsigned short* hsb   = (unsigned short*)(ws);              // 16 MB [4096][2048]
  unsigned short* wqkvt = (unsigned short*)(ws + (16 << 20)); // 24 MB [6144][2048]
  unsigned short* wot   = (unsigned short*)(ws + (40 << 20)); //  8 MB
  unsigned short* Qb    = (unsigned short*)(ws + (48 << 20)); // 16 MB [bh][s][d]
  unsigned short* Kb    = (unsigned short*)(ws + (64 << 20)); // 16 MB [bh][s][d]
  unsigned short* Vtb   = (unsigned short*)(ws + (80 << 20)); // 16 MB [bh][d][s]
  unsigned short* ctx   = (unsigned short*)(ws + (96 << 20)); // 16 MB [4096][2048]

  cvt_bf16<<<dim3(8192), dim3(256), 0, stream>>>(hs, hsb);
  transpose_cvt4<<<dim3(64, 64, 4), dim3(32, 8), 0, stream>>>(Wq, Wk, Wv, Wo, wqkvt, wot);

  gemmqkv<<<dim3(768), dim3(512), 0, stream>>>(hsb, wqkvt, bq, bk, bv, Qb, Kb, Vtb);
  attn<<<dim3(16, 32), 256, 0, stream>>>(Qb, Kb, Vtb, ctx);
  gemm128<0><<<dim3(512), 256, 0, stream>>>(ctx, wot, bo, nullptr, nullptr,
                                            (void*)out, nullptr, nullptr);
}

// Round 4
// 388.560 us; speedup vs baseline: 1.0637x; 1.0012x over previous
//
#include <hip/hip_runtime.h>
#include <cstdint>

typedef __attribute__((ext_vector_type(4))) float f32x4;
typedef __attribute__((ext_vector_type(16))) float f32x16;
typedef __attribute__((ext_vector_type(8))) __bf16 bf16x8;
typedef __attribute__((ext_vector_type(4))) unsigned short u16x4;
typedef __attribute__((ext_vector_type(2))) unsigned int u32x2;
typedef __attribute__((ext_vector_type(4))) float fvec4;

#define DEV __device__ __forceinline__
#define MFMA16(a, b, c) __builtin_amdgcn_mfma_f32_16x16x32_bf16((a), (b), (c), 0, 0, 0)
#define MFMA32(a, b, c) __builtin_amdgcn_mfma_f32_32x32x16_bf16((a), (b), (c), 0, 0, 0)

// RNE float -> bf16
DEV unsigned short f2bf(float f) {
  union { float f; uint32_t u; } c; c.f = f;
  uint32_t u = c.u;
  return (unsigned short)((u + 0x7FFFu + ((u >> 16) & 1u)) >> 16);
}

// pack two floats to 2 bf16 in one dword (round-half-up, 3 VALU ops)
DEV unsigned int pack2(float lo, float hi) {
  union { float f; uint32_t u; } a, b;
  a.f = lo; b.f = hi;
  return __builtin_amdgcn_perm(b.u + 0x8000u, a.u + 0x8000u, 0x07060302u);
}

// async global->LDS, 16B/lane; LDS dest = wave-uniform base + lane*16
DEV void gll16(const void* g, void* l) {
  __builtin_amdgcn_global_load_lds(
      (const __attribute__((address_space(1))) void*)(uintptr_t)g,
      (__attribute__((address_space(3))) void*)(uint32_t)(uintptr_t)l,
      16, 0, 0);
}

// ---------------- elementwise fp32 -> bf16 ----------------
__global__ void cvt_bf16(const float* __restrict__ src, unsigned short* __restrict__ dst) {
  int i = (blockIdx.x * 256 + threadIdx.x) * 4;
  fvec4 v = *(const fvec4*)(src + i);
  u16x4 o;
  o[0] = f2bf(v[0]); o[1] = f2bf(v[1]); o[2] = f2bf(v[2]); o[3] = f2bf(v[3]);
  *(u16x4*)(dst + i) = o;
}

// ---------------- 4x fused: W [K][N] fp32 -> WT [N][K] bf16 ----------------
__global__ void transpose_cvt4(const float* __restrict__ W0, const float* __restrict__ W1,
                               const float* __restrict__ W2, const float* __restrict__ W3,
                               unsigned short* __restrict__ Dqkv, unsigned short* __restrict__ Do) {
  __shared__ float t[32][33];
  const float* W = blockIdx.z == 0 ? W0 : blockIdx.z == 1 ? W1 : blockIdx.z == 2 ? W2 : W3;
  unsigned short* WT = blockIdx.z < 3 ? Dqkv + (size_t)blockIdx.z * 2048 * 2048 : Do;
  int n0 = blockIdx.x * 32, k0 = blockIdx.y * 32;
  int x = threadIdx.x, y = threadIdx.y;  // block (32,8)
  #pragma unroll
  for (int i = 0; i < 32; i += 8)
    t[y + i][x] = W[(size_t)(k0 + y + i) * 2048 + n0 + x];
  __syncthreads();
  #pragma unroll
  for (int i = 0; i < 32; i += 8)
    WT[(size_t)(n0 + y + i) * 2048 + k0 + x] = f2bf(t[x][y + i]);
}

// softmax scale folded into Q (exp2 domain): rsqrt(DH)*log2(e)
constexpr float QSC = 0.08838834764831845f * 1.4426950408889634f;

// ---------------- 128x128-tile GEMM (MODE 0: C = A@Bt^T + b0, fp32 out) ----------------
template <int MODE>
__global__ __launch_bounds__(256, 2) void gemm128(
    const unsigned short* __restrict__ A,
    const unsigned short* __restrict__ Bt,
    const float* __restrict__ b0, const float* __restrict__ b1,
    const float* __restrict__ b2,
    void* __restrict__ o0, void* __restrict__ o1, void* __restrict__ o2) {
  __shared__ unsigned short As[128 * 64];
  __shared__ unsigned short Bs[128 * 64];
  const int id = blockIdx.x;
  const int m0 = (((id & 7) << 2) | ((id >> 3) & 3)) * 128;
  const int n0 = (id >> 5) * 128;
  const int tid = threadIdx.x;
  const int wave = tid >> 6, lid = tid & 63;
  const int l16 = lid & 15, lq = lid >> 4;
  const int wm = (wave >> 1) * 64, wn = (wave & 1) * 64;

  const int srow = lid >> 3;
  const int sgrp = (lid & 7) ^ srow;

  f32x4 acc[4][4] = {};

  for (int k0 = 0; k0 < 2048; k0 += 64) {
    #pragma unroll
    for (int i = 0; i < 4; ++i) {
      const int t = wave * 4 + i;
      const int r = t * 8 + srow;
      gll16(A + (size_t)(m0 + r) * 2048 + k0 + sgrp * 8, (char*)As + t * 1024 + lid * 16);
      gll16(Bt + (size_t)(n0 + r) * 2048 + k0 + sgrp * 8, (char*)Bs + t * 1024 + lid * 16);
    }
    __syncthreads();
    #pragma unroll
    for (int kk = 0; kk < 2; ++kk) {
      const int G = kk * 4 + lq;
      bf16x8 af[4], bfr[4];
      #pragma unroll
      for (int i = 0; i < 4; ++i)
        af[i] = *(const bf16x8*)(As + (wm + i * 16 + l16) * 64 + ((G ^ (l16 & 7)) << 3));
      #pragma unroll
      for (int j = 0; j < 4; ++j)
        bfr[j] = *(const bf16x8*)(Bs + (wn + j * 16 + l16) * 64 + ((G ^ (l16 & 7)) << 3));
      #pragma unroll
      for (int i = 0; i < 4; ++i)
        #pragma unroll
        for (int j = 0; j < 4; ++j)
          acc[i][j] = MFMA16(af[i], bfr[j], acc[i][j]);
    }
    __syncthreads();
  }

  #pragma unroll
  for (int j = 0; j < 4; ++j) {
    const int c = n0 + wn + j * 16 + l16;
    const float bv = b0[c];
    #pragma unroll
    for (int i = 0; i < 4; ++i)
      #pragma unroll
      for (int r = 0; r < 4; ++r) {
        const int row = m0 + wm + i * 16 + lq * 4 + r;
        ((float*)o0)[(size_t)row * 2048 + c] = acc[i][j][r] + bv;
      }
  }
}

// ---------------- 256x192-tile QKV GEMM, 2 sync-events per K-tile ----------------
// Grid 512 = 2 exact rounds of 256 CUs. 8 waves 2Mx4N, per-wave 128x48.
// LDS 112KB: A[2][256][64] 64KB + B[2][192][64] 48KB, 1 block/CU.
// Per K-tile: RDALL (16 A + 6 B ds_read_b128 into regs) -> lgkm(0) -> 24 MFMA
// (h0) -> BAR -> stage tile t+2 (7 gll16, flies under h1) -> 24 MFMA (h1,
// regs only) -> vmcnt(7) -> BAR.
// RACE FIX vs prior attempt: staging is distributed across waves (each wave
// stages 8 rows/unit), so a wave's vmcnt only proves ITS OWN DMA done. The
// read of buf c must sit after a {vmcnt; barrier} PAIR (barrier publishes
// completion cross-wave). Loop is rotated so iter t's RDALL_(c) immediately
// follows iter t-1's trailing VM7_;BAR_. Overwrite side: mid-iter BAR_ is
// reached only after every wave's lgkmcnt(0) drained its buf-c reads.
__global__ __launch_bounds__(512, 2) void gemmqkv(
    const unsigned short* __restrict__ A,
    const unsigned short* __restrict__ Bt,
    const float* __restrict__ b0, const float* __restrict__ b1,
    const float* __restrict__ b2,
    unsigned short* __restrict__ oQ, unsigned short* __restrict__ oK,
    unsigned short* __restrict__ oV) {
  __shared__ unsigned short Als[2 * 256 * 64];  // 64 KB
  __shared__ unsigned short Bls[2 * 192 * 64];  // 48 KB

  const int id = blockIdx.x;              // 512 blocks
  const int xcd = id & 7, loc = id >> 3;  // loc 0..63
  const int nt = xcd * 4 + (loc >> 4);    // B-panel-hot per XCD (R2-proven)
  const int mt = loc & 15;                // A streams via L3
  const int m0 = mt << 8, n0 = nt * 192;

  const int tid = threadIdx.x;
  const int wave = tid >> 6, lid = tid & 63;
  const int l16 = lid & 15, lq = lid >> 4;
  const int wr = wave >> 2, wc = wave & 3;      // 2M x 4N waves
  const int srow = tid >> 3;                    // staging row-in-unit (0..63)
  const int g8 = ((tid & 7) ^ (srow & 7)) * 8;  // pre-swizzled global k-chunk

  f32x4 acc[8][3] = {};
  bf16x8 aq[8][2], bq[3][2];

#define STA_(c, kt) do { \
    _Pragma("unroll") for (int u = 0; u < 4; ++u) \
      gll16(A + (size_t)(m0 + u * 64 + srow) * 2048 + ((kt) << 6) + g8, \
            (char*)Als + (c) * 32768 + u * 8192 + tid * 16); \
  } while (0)

#define STB_(c, kt) do { \
    _Pragma("unroll") for (int u = 0; u < 3; ++u) \
      gll16(Bt + (size_t)(n0 + u * 64 + srow) * 2048 + ((kt) << 6) + g8, \
            (char*)Bls + (c) * 24576 + u * 8192 + tid * 16); \
  } while (0)

#define RDALL_(c) do { \
    _Pragma("unroll") for (int mf = 0; mf < 8; ++mf) { \
      const int row = wr * 128 + mf * 16 + l16; \
      _Pragma("unroll") for (int kk = 0; kk < 2; ++kk) \
        aq[mf][kk] = *(const bf16x8*)(Als + (c) * 16384 + row * 64 + \
                                      (((kk * 4 + lq) ^ (row & 7)) << 3)); \
    } \
    _Pragma("unroll") for (int n = 0; n < 3; ++n) { \
      const int bg = wc * 48 + n * 16 + l16; \
      _Pragma("unroll") for (int kk = 0; kk < 2; ++kk) \
        bq[n][kk] = *(const bf16x8*)(Bls + (c) * 12288 + bg * 64 + \
                                     (((kk * 4 + lq) ^ (bg & 7)) << 3)); \
    } } while (0)

#define MM_(h) do { \
    _Pragma("unroll") for (int m = 0; m < 4; ++m) \
      _Pragma("unroll") for (int n = 0; n < 3; ++n) \
        _Pragma("unroll") for (int kk = 0; kk < 2; ++kk) \
          acc[(h) * 4 + m][n] = MFMA16(aq[(h) * 4 + m][kk], bq[n][kk], acc[(h) * 4 + m][n]); \
  } while (0)

#define SB_ __builtin_amdgcn_sched_barrier(0)
#define BAR_ __builtin_amdgcn_s_barrier()
#define LGKM_ asm volatile("s_waitcnt lgkmcnt(0)" ::: "memory")
#define VM7_ asm volatile("s_waitcnt vmcnt(7)" ::: "memory")

  // prologue: tile0 (7 units) + tile1 (7 units); vmcnt(7) completes tile0
  // (own share); BAR publishes cross-wave.
  STA_(0, 0); STB_(0, 0);
  STA_(1, 1); STB_(1, 1);
  VM7_;
  BAR_;

  #pragma unroll 1
  for (int t = 0; t < 32; ++t) {
    const int c = t & 1;
    const int tn = (t + 2 < 32) ? t + 2 : 31;  // clamped tail restage: dead-safe
    RDALL_(c);                       // buf c published by prior VM7_;BAR_
    SB_; LGKM_; SB_;                 // own ds_reads drained
    __builtin_amdgcn_s_setprio(1); MM_(0); __builtin_amdgcn_s_setprio(0);
    SB_; BAR_;                       // all waves' reads of buf c complete
    STA_(c, tn); STB_(c, tn);        // overwrite buf c; flies under MFMA h1
    SB_;
    __builtin_amdgcn_s_setprio(1); MM_(1); __builtin_amdgcn_s_setprio(0);
    SB_; VM7_;                       // own share of tile t+1 staging complete
    BAR_;                            // publish: buf c^1 ready for next iter
  }
  asm volatile("s_waitcnt vmcnt(0)" ::: "memory");  // drain before LDS teardown

  // epilogue: QKV split + bias; Q scaled; V transposed to [bh][d][s].
  // N=192 straddles Q/K/V boundaries -> 'which' per column (16-aligned, so
  // uniform within each fragment).
  #pragma unroll
  for (int n = 0; n < 3; ++n) {
    const int cgl = n0 + wc * 48 + n * 16 + l16;
    const int which = cgl >> 11;  // 0=Q 1=K 2=V
    const int hd = cgl & 2047;
    const int h = hd >> 7, d = hd & 127;
    const float* bp = which == 0 ? b0 : which == 1 ? b1 : b2;
    const float bv = bp[hd];
    if (which == 2) {
      #pragma unroll
      for (int m = 0; m < 8; ++m) {
        const int row0 = m0 + wr * 128 + m * 16 + lq * 4;
        const int bb = row0 >> 11, s0 = row0 & 2047;
        u16x4 pv;
        #pragma unroll
        for (int r = 0; r < 4; ++r) pv[r] = f2bf(acc[m][n][r] + bv);
        *(u16x4*)(oV + ((size_t)((bb * 16 + h) * 128 + d)) * 2048 + s0) = pv;
      }
    } else {
      const float sc = which == 0 ? QSC : 1.0f;
      unsigned short* op = which == 0 ? oQ : oK;
      #pragma unroll
      for (int m = 0; m < 8; ++m)
        #pragma unroll
        for (int r = 0; r < 4; ++r) {
          const int row = m0 + wr * 128 + m * 16 + lq * 4 + r;
          const int bb = row >> 11, s = row & 2047;
          op[(size_t)((bb * 16 + h) * 2048 + s) * 128 + d] = f2bf((acc[m][n][r] + bv) * sc);
        }
    }
  }
#undef STA_
#undef STB_
#undef RDALL_
#undef MM_
#undef SB_
#undef BAR_
#undef LGKM_
#undef VM7_
}

// ---------------- flash attention: 32x32x16 MFMA, 128-q blocks ----------------
__global__ __launch_bounds__(256, 2) void attn(
    const unsigned short* __restrict__ Q,
    const unsigned short* __restrict__ K,
    const unsigned short* __restrict__ Vt,
    unsigned short* __restrict__ ctx) {
  __shared__ unsigned short Ks[64 * 128];      // [kr][16B-chunk ^ (kr&15)] 16KB
  __shared__ unsigned short Vts[128 * 64];     // [d][16B-chunk ^ (d&7)]    16KB
  __shared__ unsigned short Ps[4 * 32 * 64];   // per-wave [q][chunk ^ (q&7)] 16KB

  const int bh = blockIdx.y;
  const int jq = (bh < 16) ? (15 - (int)blockIdx.x) : (int)blockIdx.x;
  const int q0 = jq * 128;
  const int b = bh >> 4, h = bh & 15;
  const unsigned short* Qh = Q + (size_t)bh * 2048 * 128;
  const unsigned short* Kh = K + (size_t)bh * 2048 * 128;
  const unsigned short* Vth = Vt + (size_t)bh * 128 * 2048;

  const int tid = threadIdx.x;
  const int wave = tid >> 6, lid = tid & 63;
  const int l32 = lid & 31, half = lid >> 5;
  const int qrow = q0 + wave * 32 + l32;
  unsigned short* Pw = Ps + wave * 2048 + l32 * 64;
  const int qsw = l32 & 7;

  bf16x8 qf[8];
  #pragma unroll
  for (int ds = 0; ds < 8; ++ds)
    qf[ds] = *(const bf16x8*)(Qh + (size_t)qrow * 128 + ds * 16 + half * 8);

  float m_i = -1e30f, l_i = 0.f;
  f32x16 acc[4] = {};

  const int ntiles = 2 * jq + 2;
  for (int jt = 0; jt < ntiles; ++jt) {
    const int k0 = jt * 64;
    #pragma unroll
    for (int ii = 0; ii < 4; ++ii) {
      const int t = wave * 4 + ii;
      const int r = t * 4 + (lid >> 4);
      const int g = (lid & 15) ^ (r & 15);
      gll16(Kh + (size_t)(k0 + r) * 128 + g * 8, (char*)Ks + t * 1024 + lid * 16);
    }
    #pragma unroll
    for (int ii = 0; ii < 4; ++ii) {
      const int t = wave * 4 + ii;
      const int d = t * 8 + (lid >> 3);
      const int g = (lid & 7) ^ (d & 7);
      gll16(Vth + (size_t)d * 2048 + k0 + g * 8, (char*)Vts + t * 1024 + lid * 16);
    }
    __syncthreads();

    f32x16 sacc[2] = {};
    #pragma unroll
    for (int ds = 0; ds < 8; ++ds) {
      #pragma unroll
      for (int mb = 0; mb < 2; ++mb) {
        const int kr = mb * 32 + l32;
        bf16x8 af = *(const bf16x8*)(Ks + kr * 128 + (((ds * 2 + half) ^ (kr & 15)) << 3));
        sacc[mb] = MFMA32(af, qf[ds], sacc[mb]);
      }
    }

    if (jt >= 2 * jq) {
      #pragma unroll
      for (int mb = 0; mb < 2; ++mb)
        #pragma unroll
        for (int i = 0; i < 16; ++i) {
          const int kg = k0 + mb * 32 + (i & 3) + 8 * (i >> 2) + 4 * half;
          if (kg > qrow) sacc[mb][i] = -1e30f;
        }
    }

    float tmax = -1e30f;
    #pragma unroll
    for (int mb = 0; mb < 2; ++mb)
      #pragma unroll
      for (int i = 0; i < 16; ++i) tmax = fmaxf(tmax, sacc[mb][i]);
    tmax = fmaxf(tmax, __shfl_xor(tmax, 32));

    const float mnew = fmaxf(m_i, tmax);
    const float alpha = exp2f(m_i - mnew);
    m_i = mnew;

    float ps = 0.f;
    #pragma unroll
    for (int mb = 0; mb < 2; ++mb) {
      #pragma unroll
      for (int i = 0; i < 16; ++i) {
        sacc[mb][i] = exp2f(sacc[mb][i] - mnew);
        ps += sacc[mb][i];
      }
      #pragma unroll
      for (int u = 0; u < 4; ++u) {
        u32x2 w;
        w[0] = pack2(sacc[mb][4 * u], sacc[mb][4 * u + 1]);
        w[1] = pack2(sacc[mb][4 * u + 2], sacc[mb][4 * u + 3]);
        *(u32x2*)(Pw + (((u + mb * 4) ^ qsw) << 3) + half * 4) = w;
      }
    }
    ps += __shfl_xor(ps, 32);
    l_i = l_i * alpha + ps;
    #pragma unroll
    for (int db = 0; db < 4; ++db)
      #pragma unroll
      for (int i = 0; i < 16; ++i) acc[db][i] *= alpha;

    #pragma unroll
    for (int ks = 0; ks < 4; ++ks) {
      bf16x8 pf = *(const bf16x8*)(Pw + (((ks * 2 + half) ^ qsw) << 3));
      #pragma unroll
      for (int db = 0; db < 4; ++db) {
        const int d = db * 32 + l32;
        bf16x8 vf = *(const bf16x8*)(Vts + d * 64 + (((ks * 2 + half) ^ (d & 7)) << 3));
        acc[db] = MFMA32(vf, pf, acc[db]);
      }
    }
    __syncthreads();
  }

  const float inv = 1.f / l_i;
  const size_t base = ((size_t)(b * 2048 + qrow)) * 2048 + h * 128;
  #pragma unroll
  for (int db = 0; db < 4; ++db) {
    #pragma unroll
    for (int u = 0; u < 4; ++u) {
      u32x2 w;
      w[0] = pack2(acc[db][4 * u] * inv, acc[db][4 * u + 1] * inv);
      w[1] = pack2(acc[db][4 * u + 2] * inv, acc[db][4 * u + 3] * inv);
      *(u32x2*)(ctx + base + db * 32 + 8 * u + 4 * half) = w;
    }
  }
}

// ---------------- launch ----------------
extern "C" void kernel_launch(void* const* d_in, const int* in_sizes, int n_in,
                              void* d_out, int out_size, void* d_ws, size_t ws_size,
                              hipStream_t stream) {
  const float* hs = (const float*)d_in[0];
  const float* Wq = (const float*)d_in[1];
  const float* bq = (const float*)d_in[2];
  const float* Wk = (const float*)d_in[3];
  const float* bk = (const float*)d_in[4];
  const float* Wv = (const float*)d_in[5];
  const float* bv = (const float*)d_in[6];
  const float* Wo = (const float*)d_in[7];
  const float* bo = (const float*)d_in[8];
  float* out = (float*)d_out;

  char* ws = (char*)d_ws;
  unsigned short* hsb   = (unsigned short*)(ws);              // 16 MB [4096][2048]
  unsigned short* wqkvt = (unsigned short*)(ws + (16 << 20)); // 24 MB [6144][2048]
  unsigned short* wot   = (unsigned short*)(ws + (40 << 20)); //  8 MB
  unsigned short* Qb    = (unsigned short*)(ws + (48 << 20)); // 16 MB [bh][s][d]
  unsigned short* Kb    = (unsigned short*)(ws + (64 << 20)); // 16 MB [bh][s][d]
  unsigned short* Vtb   = (unsigned short*)(ws + (80 << 20)); // 16 MB [bh][d][s]
  unsigned short* ctx   = (unsigned short*)(ws + (96 << 20)); // 16 MB [4096][2048]

  cvt_bf16<<<dim3(8192), dim3(256), 0, stream>>>(hs, hsb);
  transpose_cvt4<<<dim3(64, 64, 4), dim3(32, 8), 0, stream>>>(Wq, Wk, Wv, Wo, wqkvt, wot);

  gemmqkv<<<dim3(512), dim3(512), 0, stream>>>(hsb, wqkvt, bq, bk, bv, Qb, Kb, Vtb);
  attn<<<dim3(16, 32), 256, 0, stream>>>(Qb, Kb, Vtb, ctx);
  gemm128<0><<<dim3(512), 256, 0, stream>>>(ctx, wot, bo, nullptr, nullptr,
                                            (void*)out, nullptr, nullptr);
}

// Round 5
// 381.963 us; speedup vs baseline: 1.0821x; 1.0173x over previous
//
#include <hip/hip_runtime.h>
#include <cstdint>

typedef __attribute__((ext_vector_type(4))) float f32x4;
typedef __attribute__((ext_vector_type(16))) float f32x16;
typedef __attribute__((ext_vector_type(8))) __bf16 bf16x8;
typedef __attribute__((ext_vector_type(4))) unsigned short u16x4;
typedef __attribute__((ext_vector_type(2))) unsigned int u32x2;
typedef __attribute__((ext_vector_type(4))) float fvec4;

#define DEV __device__ __forceinline__
#define MFMA16(a, b, c) __builtin_amdgcn_mfma_f32_16x16x32_bf16((a), (b), (c), 0, 0, 0)
#define MFMA32(a, b, c) __builtin_amdgcn_mfma_f32_32x32x16_bf16((a), (b), (c), 0, 0, 0)

// RNE float -> bf16
DEV unsigned short f2bf(float f) {
  union { float f; uint32_t u; } c; c.f = f;
  uint32_t u = c.u;
  return (unsigned short)((u + 0x7FFFu + ((u >> 16) & 1u)) >> 16);
}

// pack two floats to 2 bf16 in one dword (round-half-up, 3 VALU ops)
DEV unsigned int pack2(float lo, float hi) {
  union { float f; uint32_t u; } a, b;
  a.f = lo; b.f = hi;
  return __builtin_amdgcn_perm(b.u + 0x8000u, a.u + 0x8000u, 0x07060302u);
}

// async global->LDS, 16B/lane; LDS dest = wave-uniform base + lane*16
DEV void gll16(const void* g, void* l) {
  __builtin_amdgcn_global_load_lds(
      (const __attribute__((address_space(1))) void*)(uintptr_t)g,
      (__attribute__((address_space(3))) void*)(uint32_t)(uintptr_t)l,
      16, 0, 0);
}

// ---------------- elementwise fp32 -> bf16 ----------------
__global__ void cvt_bf16(const float* __restrict__ src, unsigned short* __restrict__ dst) {
  int i = (blockIdx.x * 256 + threadIdx.x) * 4;
  fvec4 v = *(const fvec4*)(src + i);
  u16x4 o;
  o[0] = f2bf(v[0]); o[1] = f2bf(v[1]); o[2] = f2bf(v[2]); o[3] = f2bf(v[3]);
  *(u16x4*)(dst + i) = o;
}

// ---------------- 4x fused: W [K][N] fp32 -> WT [N][K] bf16 ----------------
__global__ void transpose_cvt4(const float* __restrict__ W0, const float* __restrict__ W1,
                               const float* __restrict__ W2, const float* __restrict__ W3,
                               unsigned short* __restrict__ Dqkv, unsigned short* __restrict__ Do) {
  __shared__ float t[32][33];
  const float* W = blockIdx.z == 0 ? W0 : blockIdx.z == 1 ? W1 : blockIdx.z == 2 ? W2 : W3;
  unsigned short* WT = blockIdx.z < 3 ? Dqkv + (size_t)blockIdx.z * 2048 * 2048 : Do;
  int n0 = blockIdx.x * 32, k0 = blockIdx.y * 32;
  int x = threadIdx.x, y = threadIdx.y;  // block (32,8)
  #pragma unroll
  for (int i = 0; i < 32; i += 8)
    t[y + i][x] = W[(size_t)(k0 + y + i) * 2048 + n0 + x];
  __syncthreads();
  #pragma unroll
  for (int i = 0; i < 32; i += 8)
    WT[(size_t)(n0 + y + i) * 2048 + k0 + x] = f2bf(t[x][y + i]);
}

// softmax scale folded into Q (exp2 domain): rsqrt(DH)*log2(e)
constexpr float QSC = 0.08838834764831845f * 1.4426950408889634f;

// ---------------- 128x128-tile GEMM (MODE 0: C = A@Bt^T + b0, fp32 out) ----------------
template <int MODE>
__global__ __launch_bounds__(256, 2) void gemm128(
    const unsigned short* __restrict__ A,
    const unsigned short* __restrict__ Bt,
    const float* __restrict__ b0, const float* __restrict__ b1,
    const float* __restrict__ b2,
    void* __restrict__ o0, void* __restrict__ o1, void* __restrict__ o2) {
  __shared__ unsigned short As[128 * 64];
  __shared__ unsigned short Bs[128 * 64];
  const int id = blockIdx.x;
  const int m0 = (((id & 7) << 2) | ((id >> 3) & 3)) * 128;
  const int n0 = (id >> 5) * 128;
  const int tid = threadIdx.x;
  const int wave = tid >> 6, lid = tid & 63;
  const int l16 = lid & 15, lq = lid >> 4;
  const int wm = (wave >> 1) * 64, wn = (wave & 1) * 64;

  const int srow = lid >> 3;
  const int sgrp = (lid & 7) ^ srow;

  f32x4 acc[4][4] = {};

  for (int k0 = 0; k0 < 2048; k0 += 64) {
    #pragma unroll
    for (int i = 0; i < 4; ++i) {
      const int t = wave * 4 + i;
      const int r = t * 8 + srow;
      gll16(A + (size_t)(m0 + r) * 2048 + k0 + sgrp * 8, (char*)As + t * 1024 + lid * 16);
      gll16(Bt + (size_t)(n0 + r) * 2048 + k0 + sgrp * 8, (char*)Bs + t * 1024 + lid * 16);
    }
    __syncthreads();
    #pragma unroll
    for (int kk = 0; kk < 2; ++kk) {
      const int G = kk * 4 + lq;
      bf16x8 af[4], bfr[4];
      #pragma unroll
      for (int i = 0; i < 4; ++i)
        af[i] = *(const bf16x8*)(As + (wm + i * 16 + l16) * 64 + ((G ^ (l16 & 7)) << 3));
      #pragma unroll
      for (int j = 0; j < 4; ++j)
        bfr[j] = *(const bf16x8*)(Bs + (wn + j * 16 + l16) * 64 + ((G ^ (l16 & 7)) << 3));
      #pragma unroll
      for (int i = 0; i < 4; ++i)
        #pragma unroll
        for (int j = 0; j < 4; ++j)
          acc[i][j] = MFMA16(af[i], bfr[j], acc[i][j]);
    }
    __syncthreads();
  }

  #pragma unroll
  for (int j = 0; j < 4; ++j) {
    const int c = n0 + wn + j * 16 + l16;
    const float bv = b0[c];
    #pragma unroll
    for (int i = 0; i < 4; ++i)
      #pragma unroll
      for (int r = 0; r < 4; ++r) {
        const int row = m0 + wm + i * 16 + lq * 4 + r;
        ((float*)o0)[(size_t)row * 2048 + c] = acc[i][j][r] + bv;
      }
  }
}

// ---------------- 256x192-tile QKV GEMM, ILP-overlapped ----------------
// Grid 512 = 2 exact rounds of 256 CUs. 8 waves 4Mx2N, per-wave 64x96
// (4x2 arrangement cuts LDS read replication: A x2 + B x4 = 160KB/CU/K-tile
// vs 176KB for 2x4). LDS 112KB: A[2][256][64] + B[2][192][64], 1 block/CU.
// KEY CHANGE vs round 4 (37% MfmaUtil, serialized): region 1 has NO
// sched_barrier / manual lgkm between the 20 ds_read_b128 and the first 24
// MFMAs -- the compiler tracks deps on its own ds_reads and emits counted
// lgkmcnt, so m0/m1 MFMAs overlap the remaining read drain (reads ordered
// B[12], A[8] so region-1 MFMAs depend only on the first 16).
// Sync skeleton identical to round 4 (passed):
//   [BAR published buf c] reads+MFMA(m0,m1) ; LGKM ; BAR ; stage(c,t+2) ;
//   MFMA(m2,m3 pure-reg, covers gll issue) ; VM7 ; BAR
// Cross-wave hazards: reads of buf c follow a {vmcnt;BAR} pair; overwrite of
// buf c follows {LGKM;BAR} (all waves' reads complete).
__global__ __launch_bounds__(512, 2) void gemmqkv(
    const unsigned short* __restrict__ A,
    const unsigned short* __restrict__ Bt,
    const float* __restrict__ b0, const float* __restrict__ b1,
    const float* __restrict__ b2,
    unsigned short* __restrict__ oQ, unsigned short* __restrict__ oK,
    unsigned short* __restrict__ oV) {
  __shared__ unsigned short Als[2 * 256 * 64];  // 64 KB
  __shared__ unsigned short Bls[2 * 192 * 64];  // 48 KB

  const int id = blockIdx.x;              // 512 blocks
  const int xcd = id & 7, loc = id >> 3;  // loc 0..63
  const int nt = xcd * 4 + (loc >> 4);    // B-panel-hot per XCD
  const int mt = loc & 15;                // A streams via L3
  const int m0 = mt << 8, n0 = nt * 192;

  const int tid = threadIdx.x;
  const int wave = tid >> 6, lid = tid & 63;
  const int l16 = lid & 15, lq = lid >> 4;
  const int wr = wave >> 1, wc2 = wave & 1;     // 4M x 2N waves
  const int srow = tid >> 3;                    // staging row-in-unit (0..63)
  const int g8 = ((tid & 7) ^ (srow & 7)) * 8;  // pre-swizzled global k-chunk

  f32x4 acc[4][6] = {};
  bf16x8 aq[4][2], bq[6][2];

#define STA_(c, kt) do { \
    _Pragma("unroll") for (int u = 0; u < 4; ++u) \
      gll16(A + (size_t)(m0 + u * 64 + srow) * 2048 + ((kt) << 6) + g8, \
            (char*)Als + (c) * 32768 + u * 8192 + tid * 16); \
  } while (0)

#define STB_(c, kt) do { \
    _Pragma("unroll") for (int u = 0; u < 3; ++u) \
      gll16(Bt + (size_t)(n0 + u * 64 + srow) * 2048 + ((kt) << 6) + g8, \
            (char*)Bls + (c) * 24576 + u * 8192 + tid * 16); \
  } while (0)

#define RDB_(c) do { \
    _Pragma("unroll") for (int n = 0; n < 6; ++n) { \
      const int bg = wc2 * 96 + n * 16 + l16; \
      _Pragma("unroll") for (int kk = 0; kk < 2; ++kk) \
        bq[n][kk] = *(const bf16x8*)(Bls + (c) * 12288 + bg * 64 + \
                                     (((kk * 4 + lq) ^ (bg & 7)) << 3)); \
    } } while (0)

#define RDA_(c) do { \
    _Pragma("unroll") for (int m = 0; m < 4; ++m) { \
      const int row = wr * 64 + m * 16 + l16; \
      _Pragma("unroll") for (int kk = 0; kk < 2; ++kk) \
        aq[m][kk] = *(const bf16x8*)(Als + (c) * 16384 + row * 64 + \
                                     (((kk * 4 + lq) ^ (row & 7)) << 3)); \
    } } while (0)

#define MMH_(h) do { \
    _Pragma("unroll") for (int m = (h) * 2; m < (h) * 2 + 2; ++m) \
      _Pragma("unroll") for (int n = 0; n < 6; ++n) \
        _Pragma("unroll") for (int kk = 0; kk < 2; ++kk) \
          acc[m][n] = MFMA16(aq[m][kk], bq[n][kk], acc[m][n]); \
  } while (0)

#define SB_ __builtin_amdgcn_sched_barrier(0)
#define BAR_ __builtin_amdgcn_s_barrier()
#define LGKM_ asm volatile("s_waitcnt lgkmcnt(0)" ::: "memory")
#define VM7_ asm volatile("s_waitcnt vmcnt(7)" ::: "memory")

  // prologue: tile0 (7 units) + tile1 (7 units); vmcnt(7) completes tile0
  // (own share); BAR publishes cross-wave.
  STA_(0, 0); STB_(0, 0);
  STA_(1, 1); STB_(1, 1);
  VM7_;
  BAR_;

  #pragma unroll 1
  for (int t = 0; t < 32; ++t) {
    const int c = t & 1;
    const int tn = (t + 2 < 32) ? t + 2 : 31;  // clamped tail restage: dead-safe
    SB_;                             // no reads hoist above the publishing BAR
    RDB_(c); RDA_(c);                // 12 B-reads then 8 A-reads
    MMH_(0);                         // m0,m1: deps = first 16 reads; compiler
                                     // interleaves + emits counted lgkmcnt
    LGKM_; SB_; BAR_;                // all waves' reads of buf c complete
    STA_(c, tn); STB_(c, tn);        // overwrite buf c; flies under MMH_(1)
    SB_;
    __builtin_amdgcn_s_setprio(1); MMH_(1); __builtin_amdgcn_s_setprio(0);
    SB_; VM7_;                       // own share of tile t+1 staging complete
    BAR_;                            // publish: buf c^1 ready for next iter
  }
  asm volatile("s_waitcnt vmcnt(0)" ::: "memory");  // drain before LDS teardown

  // epilogue: QKV split + bias; Q scaled; V transposed to [bh][d][s].
  // 96-col wave window can straddle Q/K/V boundaries -> 'which' per n-frag
  // (16-aligned, uniform within each fragment).
  #pragma unroll
  for (int n = 0; n < 6; ++n) {
    const int cgl = n0 + wc2 * 96 + n * 16 + l16;
    const int which = cgl >> 11;  // 0=Q 1=K 2=V
    const int hd = cgl & 2047;
    const int h = hd >> 7, d = hd & 127;
    const float* bp = which == 0 ? b0 : which == 1 ? b1 : b2;
    const float bv = bp[hd];
    if (which == 2) {
      #pragma unroll
      for (int m = 0; m < 4; ++m) {
        const int row0 = m0 + wr * 64 + m * 16 + lq * 4;
        const int bb = row0 >> 11, s0 = row0 & 2047;
        u16x4 pv;
        #pragma unroll
        for (int r = 0; r < 4; ++r) pv[r] = f2bf(acc[m][n][r] + bv);
        *(u16x4*)(oV + ((size_t)((bb * 16 + h) * 128 + d)) * 2048 + s0) = pv;
      }
    } else {
      const float sc = which == 0 ? QSC : 1.0f;
      unsigned short* op = which == 0 ? oQ : oK;
      #pragma unroll
      for (int m = 0; m < 4; ++m)
        #pragma unroll
        for (int r = 0; r < 4; ++r) {
          const int row = m0 + wr * 64 + m * 16 + lq * 4 + r;
          const int bb = row >> 11, s = row & 2047;
          op[(size_t)((bb * 16 + h) * 2048 + s) * 128 + d] = f2bf((acc[m][n][r] + bv) * sc);
        }
    }
  }
#undef STA_
#undef STB_
#undef RDB_
#undef RDA_
#undef MMH_
#undef SB_
#undef BAR_
#undef LGKM_
#undef VM7_
}

// ---------------- flash attention: 32x32x16 MFMA, 128-q blocks ----------------
__global__ __launch_bounds__(256, 2) void attn(
    const unsigned short* __restrict__ Q,
    const unsigned short* __restrict__ K,
    const unsigned short* __restrict__ Vt,
    unsigned short* __restrict__ ctx) {
  __shared__ unsigned short Ks[64 * 128];      // [kr][16B-chunk ^ (kr&15)] 16KB
  __shared__ unsigned short Vts[128 * 64];     // [d][16B-chunk ^ (d&7)]    16KB
  __shared__ unsigned short Ps[4 * 32 * 64];   // per-wave [q][chunk ^ (q&7)] 16KB

  const int bh = blockIdx.y;
  const int jq = (bh < 16) ? (15 - (int)blockIdx.x) : (int)blockIdx.x;
  const int q0 = jq * 128;
  const int b = bh >> 4, h = bh & 15;
  const unsigned short* Qh = Q + (size_t)bh * 2048 * 128;
  const unsigned short* Kh = K + (size_t)bh * 2048 * 128;
  const unsigned short* Vth = Vt + (size_t)bh * 128 * 2048;

  const int tid = threadIdx.x;
  const int wave = tid >> 6, lid = tid & 63;
  const int l32 = lid & 31, half = lid >> 5;
  const int qrow = q0 + wave * 32 + l32;
  unsigned short* Pw = Ps + wave * 2048 + l32 * 64;
  const int qsw = l32 & 7;

  bf16x8 qf[8];
  #pragma unroll
  for (int ds = 0; ds < 8; ++ds)
    qf[ds] = *(const bf16x8*)(Qh + (size_t)qrow * 128 + ds * 16 + half * 8);

  float m_i = -1e30f, l_i = 0.f;
  f32x16 acc[4] = {};

  const int ntiles = 2 * jq + 2;
  for (int jt = 0; jt < ntiles; ++jt) {
    const int k0 = jt * 64;
    #pragma unroll
    for (int ii = 0; ii < 4; ++ii) {
      const int t = wave * 4 + ii;
      const int r = t * 4 + (lid >> 4);
      const int g = (lid & 15) ^ (r & 15);
      gll16(Kh + (size_t)(k0 + r) * 128 + g * 8, (char*)Ks + t * 1024 + lid * 16);
    }
    #pragma unroll
    for (int ii = 0; ii < 4; ++ii) {
      const int t = wave * 4 + ii;
      const int d = t * 8 + (lid >> 3);
      const int g = (lid & 7) ^ (d & 7);
      gll16(Vth + (size_t)d * 2048 + k0 + g * 8, (char*)Vts + t * 1024 + lid * 16);
    }
    __syncthreads();

    f32x16 sacc[2] = {};
    #pragma unroll
    for (int ds = 0; ds < 8; ++ds) {
      #pragma unroll
      for (int mb = 0; mb < 2; ++mb) {
        const int kr = mb * 32 + l32;
        bf16x8 af = *(const bf16x8*)(Ks + kr * 128 + (((ds * 2 + half) ^ (kr & 15)) << 3));
        sacc[mb] = MFMA32(af, qf[ds], sacc[mb]);
      }
    }

    if (jt >= 2 * jq) {
      #pragma unroll
      for (int mb = 0; mb < 2; ++mb)
        #pragma unroll
        for (int i = 0; i < 16; ++i) {
          const int kg = k0 + mb * 32 + (i & 3) + 8 * (i >> 2) + 4 * half;
          if (kg > qrow) sacc[mb][i] = -1e30f;
        }
    }

    float tmax = -1e30f;
    #pragma unroll
    for (int mb = 0; mb < 2; ++mb)
      #pragma unroll
      for (int i = 0; i < 16; ++i) tmax = fmaxf(tmax, sacc[mb][i]);
    tmax = fmaxf(tmax, __shfl_xor(tmax, 32));

    const float mnew = fmaxf(m_i, tmax);
    const float alpha = exp2f(m_i - mnew);
    m_i = mnew;

    float ps = 0.f;
    #pragma unroll
    for (int mb = 0; mb < 2; ++mb) {
      #pragma unroll
      for (int i = 0; i < 16; ++i) {
        sacc[mb][i] = exp2f(sacc[mb][i] - mnew);
        ps += sacc[mb][i];
      }
      #pragma unroll
      for (int u = 0; u < 4; ++u) {
        u32x2 w;
        w[0] = pack2(sacc[mb][4 * u], sacc[mb][4 * u + 1]);
        w[1] = pack2(sacc[mb][4 * u + 2], sacc[mb][4 * u + 3]);
        *(u32x2*)(Pw + (((u + mb * 4) ^ qsw) << 3) + half * 4) = w;
      }
    }
    ps += __shfl_xor(ps, 32);
    l_i = l_i * alpha + ps;
    #pragma unroll
    for (int db = 0; db < 4; ++db)
      #pragma unroll
      for (int i = 0; i < 16; ++i) acc[db][i] *= alpha;

    #pragma unroll
    for (int ks = 0; ks < 4; ++ks) {
      bf16x8 pf = *(const bf16x8*)(Pw + (((ks * 2 + half) ^ qsw) << 3));
      #pragma unroll
      for (int db = 0; db < 4; ++db) {
        const int d = db * 32 + l32;
        bf16x8 vf = *(const bf16x8*)(Vts + d * 64 + (((ks * 2 + half) ^ (d & 7)) << 3));
        acc[db] = MFMA32(vf, pf, acc[db]);
      }
    }
    __syncthreads();
  }

  const float inv = 1.f / l_i;
  const size_t base = ((size_t)(b * 2048 + qrow)) * 2048 + h * 128;
  #pragma unroll
  for (int db = 0; db < 4; ++db) {
    #pragma unroll
    for (int u = 0; u < 4; ++u) {
      u32x2 w;
      w[0] = pack2(acc[db][4 * u] * inv, acc[db][4 * u + 1] * inv);
      w[1] = pack2(acc[db][4 * u + 2] * inv, acc[db][4 * u + 3] * inv);
      *(u32x2*)(ctx + base + db * 32 + 8 * u + 4 * half) = w;
    }
  }
}

// ---------------- launch ----------------
extern "C" void kernel_launch(void* const* d_in, const int* in_sizes, int n_in,
                              void* d_out, int out_size, void* d_ws, size_t ws_size,
                              hipStream_t stream) {
  const float* hs = (const float*)d_in[0];
  const float* Wq = (const float*)d_in[1];
  const float* bq = (const float*)d_in[2];
  const float* Wk = (const float*)d_in[3];
  const float* bk = (const float*)d_in[4];
  const float* Wv = (const float*)d_in[5];
  const float* bv = (const float*)d_in[6];
  const float* Wo = (const float*)d_in[7];
  const float* bo = (const float*)d_in[8];
  float* out = (float*)d_out;

  char* ws = (char*)d_ws;
  unsigned short* hsb   = (unsigned short*)(ws);              // 16 MB [4096][2048]
  unsigned short* wqkvt = (unsigned short*)(ws + (16 << 20)); // 24 MB [6144][2048]
  unsigned short* wot   = (unsigned short*)(ws + (40 << 20)); //  8 MB
  unsigned short* Qb    = (unsigned short*)(ws + (48 << 20)); // 16 MB [bh][s][d]
  unsigned short* Kb    = (unsigned short*)(ws + (64 << 20)); // 16 MB [bh][s][d]
  unsigned short* Vtb   = (unsigned short*)(ws + (80 << 20)); // 16 MB [bh][d][s]
  unsigned short* ctx   = (unsigned short*)(ws + (96 << 20)); // 16 MB [4096][2048]

  cvt_bf16<<<dim3(8192), dim3(256), 0, stream>>>(hs, hsb);
  transpose_cvt4<<<dim3(64, 64, 4), dim3(32, 8), 0, stream>>>(Wq, Wk, Wv, Wo, wqkvt, wot);

  gemmqkv<<<dim3(512), dim3(512), 0, stream>>>(hsb, wqkvt, bq, bk, bv, Qb, Kb, Vtb);
  attn<<<dim3(16, 32), 256, 0, stream>>>(Qb, Kb, Vtb, ctx);
  gemm128<0><<<dim3(512), 256, 0, stream>>>(ctx, wot, bo, nullptr, nullptr,
                                            (void*)out, nullptr, nullptr);
}